// Round 1
// baseline (968.321 us; speedup 1.0000x reference)
//
#include <hip/hip_runtime.h>
#include <math.h>

// Problem constants (from reference): S=8192, B=4, C=512, H=8, D=64
#define S_LEN 8192
#define BATCH 4
#define CDIM  512
#define HEADS 8
#define DDIM  64
#define MROWS (S_LEN * BATCH)   // 32768 rows, row m = s*BATCH + b, layout [S,B,C]
#define EPS_F 1e-6f

// ---------------------------------------------------------------------------
// GEMM: Y[m][n] = act( dot(X[m][:], W[n][:]) + bias[n] ),  X:[M,512] W:[512,512]
// BM=BN=128, BK=16, 256 threads, 8x8 per thread (split-half col/row layout so
// LDS reads are float4 at 16B stride => 2-way bank aliasing (free)).
// ACT: 0 = none, 1 = elu(x)+1
// ---------------------------------------------------------------------------
template<int ACT>
__global__ __launch_bounds__(256)
void gemm_xwt(const float* __restrict__ X, const float* __restrict__ W,
              const float* __restrict__ bias, float* __restrict__ Y) {
  __shared__ __align__(16) float As[16][132];
  __shared__ __align__(16) float Bs[16][132];
  const int t  = threadIdx.x;
  const int m0 = blockIdx.x * 128;
  const int n0 = blockIdx.y * 128;
  const int tr = t >> 4;     // 0..15
  const int tc = t & 15;     // 0..15

  float acc[8][8];
  #pragma unroll
  for (int i = 0; i < 8; ++i)
    #pragma unroll
    for (int j = 0; j < 8; ++j) acc[i][j] = 0.f;

  for (int kt = 0; kt < CDIM; kt += 16) {
    // Stage A (X rows) and B (W rows), k-major in LDS.
    #pragma unroll
    for (int l = 0; l < 2; ++l) {
      const int idx = t + l * 256;     // 0..511 (float4 slots of a 128x16 tile)
      const int row = idx & 127;
      const int k4  = idx >> 7;        // 0..3
      const float4 a = *(const float4*)&X[(size_t)(m0 + row) * CDIM + kt + k4 * 4];
      As[k4 * 4 + 0][row] = a.x; As[k4 * 4 + 1][row] = a.y;
      As[k4 * 4 + 2][row] = a.z; As[k4 * 4 + 3][row] = a.w;
      const float4 bv = *(const float4*)&W[(size_t)(n0 + row) * CDIM + kt + k4 * 4];
      Bs[k4 * 4 + 0][row] = bv.x; Bs[k4 * 4 + 1][row] = bv.y;
      Bs[k4 * 4 + 2][row] = bv.z; Bs[k4 * 4 + 3][row] = bv.w;
    }
    __syncthreads();
    #pragma unroll
    for (int kk = 0; kk < 16; ++kk) {
      const float4 a0 = *(const float4*)&As[kk][tr * 4];
      const float4 a1 = *(const float4*)&As[kk][64 + tr * 4];
      const float4 b0 = *(const float4*)&Bs[kk][tc * 4];
      const float4 b1 = *(const float4*)&Bs[kk][64 + tc * 4];
      const float av[8] = {a0.x, a0.y, a0.z, a0.w, a1.x, a1.y, a1.z, a1.w};
      const float bw[8] = {b0.x, b0.y, b0.z, b0.w, b1.x, b1.y, b1.z, b1.w};
      #pragma unroll
      for (int i = 0; i < 8; ++i)
        #pragma unroll
        for (int j = 0; j < 8; ++j)
          acc[i][j] = fmaf(av[i], bw[j], acc[i][j]);
    }
    __syncthreads();
  }

  // Epilogue: rows m0 + ih*64 + tr*4 + ii, cols n0 + jh*64 + tc*4 + jj
  #pragma unroll
  for (int ih = 0; ih < 2; ++ih) {
    #pragma unroll
    for (int ii = 0; ii < 4; ++ii) {
      const int m = m0 + ih * 64 + tr * 4 + ii;
      #pragma unroll
      for (int jh = 0; jh < 2; ++jh) {
        const int nb = n0 + jh * 64 + tc * 4;
        float4 o;
        float* op = &o.x;
        #pragma unroll
        for (int jj = 0; jj < 4; ++jj) {
          float v = acc[ih * 4 + ii][jh * 4 + jj] + bias[nb + jj];
          if (ACT) v = (v > 0.f) ? (v + 1.f) : expf(v);
          op[jj] = v;
        }
        *(float4*)&Y[(size_t)m * CDIM + nb] = o;
      }
    }
  }
}

// ---------------------------------------------------------------------------
// kv partial: for one (b,h) and one chunk of 256 s-rows, compute
//   kvpart[d][f] = sum_s k[s][d] * v[s][f]   (64x64)
//   ksumpart[d]  = sum_s k[s][d]
// Deterministic chunked reduction (no float atomics).
// ---------------------------------------------------------------------------
__global__ __launch_bounds__(256)
void kv_partial(const float* __restrict__ Kb, const float* __restrict__ Vb,
                float* __restrict__ kvpart, float* __restrict__ ksumpart) {
  const int bh    = blockIdx.x;        // 0..31  (b*H + h)
  const int chunk = blockIdx.y;        // 0..31  (256 s each)
  const int b = bh >> 3, h = bh & 7;
  const int t = threadIdx.x;
  __shared__ float klds[4][64];
  __shared__ float vlds[4][64];
  const int f     = t & 63;
  const int soff  = t >> 6;            // 0..3
  const int dbase = soff * 16;
  const size_t cbase = (size_t)b * CDIM + (size_t)h * DDIM;

  float kvacc[16];
  #pragma unroll
  for (int i = 0; i < 16; ++i) kvacc[i] = 0.f;
  float ksumacc = 0.f;

  for (int s4 = 0; s4 < 64; ++s4) {
    const int s = chunk * 256 + s4 * 4 + soff;
    const size_t rbase = (size_t)s * (BATCH * CDIM) + cbase;
    klds[soff][f] = Kb[rbase + f];
    vlds[soff][f] = Vb[rbase + f];
    __syncthreads();
    #pragma unroll
    for (int ss = 0; ss < 4; ++ss) {
      const float vf = vlds[ss][f];
      #pragma unroll
      for (int i = 0; i < 16; ++i)
        kvacc[i] = fmaf(klds[ss][dbase + i], vf, kvacc[i]);
    }
    if (t < 64) {
      #pragma unroll
      for (int ss = 0; ss < 4; ++ss) ksumacc += klds[ss][t];
    }
    __syncthreads();
  }

  float* kvp = &kvpart[((size_t)bh * 32 + chunk) * 4096];
  #pragma unroll
  for (int i = 0; i < 16; ++i)
    kvp[(size_t)(dbase + i) * 64 + f] = kvacc[i];
  if (t < 64)
    ksumpart[((size_t)bh * 32 + chunk) * 64 + t] = ksumacc;
}

// ---------------------------------------------------------------------------
// Reduce the 32 chunk partials -> kv[bh][64][64], ksum[bh][64]
// ---------------------------------------------------------------------------
__global__ __launch_bounds__(256)
void kv_reduce(const float* __restrict__ kvpart, const float* __restrict__ ksumpart,
               float* __restrict__ kvm, float* __restrict__ ksum) {
  const int bh = blockIdx.x;
  const int t  = threadIdx.x;
  for (int idx = t; idx < 4096; idx += 256) {
    float s = 0.f;
    for (int c = 0; c < 32; ++c)
      s += kvpart[((size_t)bh * 32 + c) * 4096 + idx];
    kvm[(size_t)bh * 4096 + idx] = s;
  }
  if (t < 64) {
    float s = 0.f;
    for (int c = 0; c < 32; ++c)
      s += ksumpart[((size_t)bh * 32 + c) * 64 + t];
    ksum[(size_t)bh * 64 + t] = s;
  }
}

// ---------------------------------------------------------------------------
// qkv: y[s][f] = (sum_d q[s][d]*kv[d][f]) / (sum_d q[s][d]*ksum[d] + EPS)
// One block = one (b,h) and 64 s-rows. Writes y in place over the q buffer
// (safe: this block is the only reader of that region, staged to LDS first).
// ---------------------------------------------------------------------------
__global__ __launch_bounds__(256)
void qkv_kernel(float* __restrict__ Qb,
                const float* __restrict__ kvm, const float* __restrict__ ksum) {
  const int bh = blockIdx.x;     // 0..31
  const int sc = blockIdx.y;     // 0..127 (64 s-rows each)
  const int b = bh >> 3, h = bh & 7;
  const int t = threadIdx.x;
  __shared__ __align__(16) float qT[64][68];   // [d][s], padded
  __shared__ __align__(16) float kvl[64][64];  // [d][f]
  __shared__ __align__(16) float ksl[64];
  const size_t cbase = (size_t)b * CDIM + (size_t)h * DDIM;

  // Stage q chunk transposed: 64 rows x 64 dims
  #pragma unroll
  for (int l = 0; l < 4; ++l) {
    const int idx  = t + l * 256;    // 0..1023 float4 slots
    const int srow = idx >> 4;       // 0..63
    const int d4   = idx & 15;       // 0..15
    const int s = sc * 64 + srow;
    const float4 q4 = *(const float4*)&Qb[(size_t)s * (BATCH * CDIM) + cbase + d4 * 4];
    qT[d4 * 4 + 0][srow] = q4.x;
    qT[d4 * 4 + 1][srow] = q4.y;
    qT[d4 * 4 + 2][srow] = q4.z;
    qT[d4 * 4 + 3][srow] = q4.w;
  }
  // Stage kv (4096 floats) and ksum (64)
  const float* kvsrc = &kvm[(size_t)bh * 4096];
  #pragma unroll
  for (int l = 0; l < 4; ++l) {
    const int idx = t + l * 256;     // float4 index
    *(float4*)&kvl[0][0 + idx * 4] = *(const float4*)&kvsrc[(size_t)idx * 4];
  }
  if (t < 16)
    *(float4*)&ksl[t * 4] = *(const float4*)&ksum[(size_t)bh * 64 + t * 4];
  __syncthreads();

  const int tr = t >> 4, tc = t & 15;
  float acc[4][4];
  #pragma unroll
  for (int i = 0; i < 4; ++i)
    #pragma unroll
    for (int j = 0; j < 4; ++j) acc[i][j] = 0.f;
  float dacc[4] = {0.f, 0.f, 0.f, 0.f};

  #pragma unroll 16
  for (int kk = 0; kk < 64; ++kk) {
    const float4 a  = *(const float4*)&qT[kk][tr * 4];
    const float4 bv = *(const float4*)&kvl[kk][tc * 4];
    const float ks = ksl[kk];
    const float av[4] = {a.x, a.y, a.z, a.w};
    const float bb[4] = {bv.x, bv.y, bv.z, bv.w};
    #pragma unroll
    for (int i = 0; i < 4; ++i) {
      dacc[i] = fmaf(av[i], ks, dacc[i]);
      #pragma unroll
      for (int j = 0; j < 4; ++j)
        acc[i][j] = fmaf(av[i], bb[j], acc[i][j]);
    }
  }

  // Write y over the (now-dead) q region.
  #pragma unroll
  for (int i = 0; i < 4; ++i) {
    const int s = sc * 64 + tr * 4 + i;
    const float inv = 1.f / (dacc[i] + EPS_F);
    float4 o;
    o.x = acc[i][0] * inv; o.y = acc[i][1] * inv;
    o.z = acc[i][2] * inv; o.w = acc[i][3] * inv;
    *(float4*)&Qb[(size_t)s * (BATCH * CDIM) + cbase + tc * 4] = o;
  }
}

// ---------------------------------------------------------------------------
extern "C" void kernel_launch(void* const* d_in, const int* in_sizes, int n_in,
                              void* d_out, int out_size, void* d_ws, size_t ws_size,
                              hipStream_t stream) {
  const float* q_in = (const float*)d_in[0];
  const float* k_in = (const float*)d_in[1];
  const float* v_in = (const float*)d_in[2];
  const float* Wq   = (const float*)d_in[3];
  const float* bq   = (const float*)d_in[4];
  const float* Wk   = (const float*)d_in[5];
  const float* bk   = (const float*)d_in[6];
  const float* Wv   = (const float*)d_in[7];
  const float* bv   = (const float*)d_in[8];
  const float* Wp   = (const float*)d_in[9];
  const float* bp   = (const float*)d_in[10];
  float* out = (float*)d_out;
  float* ws  = (float*)d_ws;

  const size_t NBUF = (size_t)MROWS * CDIM;       // 16,777,216 floats
  float* qbuf     = ws;
  float* kbuf     = qbuf + NBUF;
  float* vbuf     = kbuf + NBUF;
  float* kvpart   = vbuf + NBUF;                  // 32*32*4096 = 4,194,304
  float* ksumpart = kvpart + (size_t)32 * 32 * 4096;  // 32*32*64 = 65,536
  float* kvm      = ksumpart + (size_t)32 * 32 * 64;  // 32*4096 = 131,072
  float* ksumm    = kvm + (size_t)32 * 4096;          // 32*64 = 2,048

  const dim3 blk(256);
  const dim3 gmm(MROWS / 128, CDIM / 128);        // (256, 4)

  // 1) Projections (ELU+1 fused for Q,K)
  gemm_xwt<1><<<gmm, blk, 0, stream>>>(q_in, Wq, bq, qbuf);
  gemm_xwt<1><<<gmm, blk, 0, stream>>>(k_in, Wk, bk, kbuf);
  gemm_xwt<0><<<gmm, blk, 0, stream>>>(v_in, Wv, bv, vbuf);

  // 2) kv = sum_s k^T v (chunked, deterministic) ; ksum = sum_s k
  kv_partial<<<dim3(32, 32), blk, 0, stream>>>(kbuf, vbuf, kvpart, ksumpart);
  kv_reduce<<<dim3(32), blk, 0, stream>>>(kvpart, ksumpart, kvm, ksumm);

  // 3) y = (q @ kv) / (q . ksum + eps), in place over q buffer
  qkv_kernel<<<dim3(32, 128), blk, 0, stream>>>(qbuf, kvm, ksumm);

  // 4) Output projection -> d_out
  gemm_xwt<0><<<gmm, blk, 0, stream>>>(qbuf, Wp, bp, out);
}

// Round 2
// 366.193 us; speedup vs baseline: 2.6443x; 2.6443x over previous
//
#include <hip/hip_runtime.h>
#include <hip/hip_bf16.h>
#include <math.h>

// Problem constants: S=8192, B=4, C=512, H=8, D=64
#define S_LEN 8192
#define BATCH 4
#define CDIM  512
#define HEADS 8
#define DDIM  64
#define MROWS (S_LEN * BATCH)   // 32768 rows; row m = s*BATCH + b; layout [S,B,C]
#define EPS_F 1e-6f

typedef __attribute__((ext_vector_type(8))) short     short8_t;
typedef __attribute__((ext_vector_type(4))) short     short4_t;
typedef __attribute__((ext_vector_type(4))) float     f32x4;
typedef unsigned short ushort_t;
typedef __attribute__((ext_vector_type(4))) unsigned short ushort4_t;
typedef __attribute__((ext_vector_type(2))) unsigned short ushort2_t;

static __device__ __forceinline__ ushort_t f2bf(float f) {
  __hip_bfloat16 h = __float2bfloat16(f);   // RNE
  return *(ushort_t*)&h;
}
static __device__ __forceinline__ float bf2f(ushort_t u) {
  unsigned int x = ((unsigned int)u) << 16;
  return __uint_as_float(x);
}

// ---------------------------------------------------------------------------
// MFMA GEMM: Y[m][n] = act( sum_k X[m][k]*W[n][k] + bias[n] )
// M=32768 (or any mult of 128), N=K=512. BM=BN=128, BK=32, 256 threads,
// 4 waves in 2x2, each wave 64x64 via 4x4 frags of 16x16x32 bf16 MFMA.
// LDS: fragment-packed (frag fm: 64 lanes x 16B contiguous) => conflict-free
// ds_write_b64 staging and ds_read_b128 fragment loads.
// XBF16: X is bf16 (no conversion); else fp32 (convert while staging).
// ACT: 1 = elu(x)+1.  OUTBF16: write bf16, else fp32.
// ---------------------------------------------------------------------------
template<int ACT, int XBF16, int OUTBF16>
__global__ __launch_bounds__(256)
void gemm_mfma(const void* __restrict__ Xv, const float* __restrict__ W,
               const float* __restrict__ bias, void* __restrict__ Yv) {
  __shared__ __align__(16) ushort_t alds[4096];   // 8 frags * 512 shorts
  __shared__ __align__(16) ushort_t blds[4096];
  const int t    = threadIdx.x;
  const int m0   = blockIdx.x * 128;
  const int n0   = blockIdx.y * 128;
  const int w    = t >> 6;          // wave 0..3
  const int lane = t & 63;
  const int wm   = (w >> 1) * 64;   // wave row offset in tile
  const int wn   = (w & 1) * 64;    // wave col offset in tile

  // Staging map: packet p (0..1023) = i*256 + t ->
  //   fm = p>>7, lane_p = (p>>1)&63, half = p&1
  //   row = fm*16 + (lane_p&15), k_local = (lane_p>>4)*8 + half*4  (4 elems)
  //   LDS short index = p*4
  int row_a[4], kloc[4], ldsp[4];
  #pragma unroll
  for (int i = 0; i < 4; ++i) {
    const int p  = i * 256 + t;
    const int fm = p >> 7;
    const int lp = (p >> 1) & 63;
    row_a[i] = fm * 16 + (lp & 15);
    kloc[i]  = ((lp >> 4) & 3) * 8 + (p & 1) * 4;
    ldsp[i]  = p * 4;
  }

  f32x4 acc[4][4];
  #pragma unroll
  for (int mi = 0; mi < 4; ++mi)
    #pragma unroll
    for (int ni = 0; ni < 4; ++ni)
      acc[mi][ni] = (f32x4){0.f, 0.f, 0.f, 0.f};

  const float* Xf = (const float*)Xv;
  const ushort_t* Xh = (const ushort_t*)Xv;

  for (int kt = 0; kt < CDIM; kt += 32) {
    // ---- load tile operands to regs ----
    float4 axf[4]; ushort4_t axh[4]; float4 bxf[4];
    #pragma unroll
    for (int i = 0; i < 4; ++i) {
      const size_t ga = (size_t)(m0 + row_a[i]) * CDIM + kt + kloc[i];
      if (XBF16) axh[i] = *(const ushort4_t*)&Xh[ga];
      else       axf[i] = *(const float4*)&Xf[ga];
      const size_t gb = (size_t)(n0 + row_a[i]) * CDIM + kt + kloc[i];
      bxf[i] = *(const float4*)&W[gb];
    }
    __syncthreads();   // previous tile fully consumed
    // ---- convert + LDS write ----
    #pragma unroll
    for (int i = 0; i < 4; ++i) {
      ushort4_t pa, pb;
      if (XBF16) pa = axh[i];
      else {
        pa[0] = f2bf(axf[i].x); pa[1] = f2bf(axf[i].y);
        pa[2] = f2bf(axf[i].z); pa[3] = f2bf(axf[i].w);
      }
      pb[0] = f2bf(bxf[i].x); pb[1] = f2bf(bxf[i].y);
      pb[2] = f2bf(bxf[i].z); pb[3] = f2bf(bxf[i].w);
      *(ushort4_t*)&alds[ldsp[i]] = pa;
      *(ushort4_t*)&blds[ldsp[i]] = pb;
    }
    __syncthreads();
    // ---- fragment reads + MFMA ----
    short8_t af[4], bfr[4];
    #pragma unroll
    for (int mi = 0; mi < 4; ++mi)
      af[mi] = *(const short8_t*)&alds[((wm >> 4) + mi) * 512 + lane * 8];
    #pragma unroll
    for (int ni = 0; ni < 4; ++ni)
      bfr[ni] = *(const short8_t*)&blds[((wn >> 4) + ni) * 512 + lane * 8];
    #pragma unroll
    for (int mi = 0; mi < 4; ++mi)
      #pragma unroll
      for (int ni = 0; ni < 4; ++ni)
        acc[mi][ni] = __builtin_amdgcn_mfma_f32_16x16x32_bf16(
            af[mi], bfr[ni], acc[mi][ni], 0, 0, 0);
  }

  // ---- epilogue: C layout col=lane&15, row=(lane>>4)*4+reg ----
  float* Yf = (float*)Yv;
  ushort_t* Yh = (ushort_t*)Yv;
  float bi[4];
  int coln[4];
  #pragma unroll
  for (int ni = 0; ni < 4; ++ni) {
    coln[ni] = n0 + wn + ni * 16 + (lane & 15);
    bi[ni]   = bias[coln[ni]];
  }
  #pragma unroll
  for (int mi = 0; mi < 4; ++mi) {
    #pragma unroll
    for (int r = 0; r < 4; ++r) {
      const int m = m0 + wm + mi * 16 + (lane >> 4) * 4 + r;
      #pragma unroll
      for (int ni = 0; ni < 4; ++ni) {
        float v = acc[mi][ni][r] + bi[ni];
        if (ACT) v = (v > 0.f) ? (v + 1.f) : expf(v);
        const size_t o = (size_t)m * CDIM + coln[ni];
        if (OUTBF16) Yh[o] = f2bf(v);
        else         Yf[o] = v;
      }
    }
  }
}

// ---------------------------------------------------------------------------
// kv partial: one (b,h), one chunk of 256 s-rows:
//   kvpart[d][f] = sum_s k[s][d]*v[s][f]  (64x64) ; ksumpart[d] = sum_s k[s][d]
// bf16 inputs. Deterministic chunked reduction.
// ---------------------------------------------------------------------------
__global__ __launch_bounds__(256)
void kv_partial(const ushort_t* __restrict__ Kb, const ushort_t* __restrict__ Vb,
                float* __restrict__ kvpart, float* __restrict__ ksumpart) {
  const int bh    = blockIdx.x;        // 0..31
  const int chunk = blockIdx.y;        // 0..31 (256 s each)
  const int b = bh >> 3, h = bh & 7;
  const int t = threadIdx.x;
  __shared__ float klds[8][64];
  __shared__ float vlds[8][64];
  const int r  = t >> 5;               // 0..7 (s-row within group)
  const int c2 = (t & 31) * 2;         // d pair
  const int f     = t & 63;
  const int dbase = (t >> 6) * 16;
  const int coff  = h * DDIM;

  float kvacc[16];
  #pragma unroll
  for (int i = 0; i < 16; ++i) kvacc[i] = 0.f;
  float ksumacc = 0.f;

  for (int it = 0; it < 32; ++it) {
    const int s = chunk * 256 + it * 8 + r;
    const int m = s * BATCH + b;
    const size_t base = (size_t)m * CDIM + coff + c2;
    const ushort2_t kk = *(const ushort2_t*)&Kb[base];
    const ushort2_t vv = *(const ushort2_t*)&Vb[base];
    klds[r][c2] = bf2f(kk[0]); klds[r][c2 + 1] = bf2f(kk[1]);
    vlds[r][c2] = bf2f(vv[0]); vlds[r][c2 + 1] = bf2f(vv[1]);
    __syncthreads();
    #pragma unroll
    for (int ss = 0; ss < 8; ++ss) {
      const float vf = vlds[ss][f];
      #pragma unroll
      for (int i = 0; i < 16; ++i)
        kvacc[i] = fmaf(klds[ss][dbase + i], vf, kvacc[i]);
    }
    if (t < 64) {
      #pragma unroll
      for (int ss = 0; ss < 8; ++ss) ksumacc += klds[ss][t];
    }
    __syncthreads();
  }

  float* kvp = &kvpart[((size_t)bh * 32 + chunk) * 4096];
  #pragma unroll
  for (int i = 0; i < 16; ++i)
    kvp[(size_t)(dbase + i) * 64 + f] = kvacc[i];
  if (t < 64)
    ksumpart[((size_t)bh * 32 + chunk) * 64 + t] = ksumacc;
}

// ---------------------------------------------------------------------------
__global__ __launch_bounds__(256)
void kv_reduce(const float* __restrict__ kvpart, const float* __restrict__ ksumpart,
               float* __restrict__ kvm, float* __restrict__ ksum) {
  const int bh = blockIdx.x;
  const int t  = threadIdx.x;
  for (int idx = t; idx < 4096; idx += 256) {
    float s = 0.f;
    for (int c = 0; c < 32; ++c)
      s += kvpart[((size_t)bh * 32 + c) * 4096 + idx];
    kvm[(size_t)bh * 4096 + idx] = s;
  }
  if (t < 64) {
    float s = 0.f;
    for (int c = 0; c < 32; ++c)
      s += ksumpart[((size_t)bh * 32 + c) * 64 + t];
    ksum[(size_t)bh * 64 + t] = s;
  }
}

// ---------------------------------------------------------------------------
// qkv: y[s][f] = (sum_d q[s][d]*kv[d][f]) / (sum_d q[s][d]*ksum[d] + EPS)
// q bf16 in, y bf16 out (in place over the q buffer region; block reads its
// own 64 rows fully into LDS first).
// ---------------------------------------------------------------------------
__global__ __launch_bounds__(256)
void qkv_kernel(ushort_t* __restrict__ Qb,
                const float* __restrict__ kvm, const float* __restrict__ ksum) {
  const int bh = blockIdx.x;     // 0..31
  const int sc = blockIdx.y;     // 0..127
  const int b = bh >> 3, h = bh & 7;
  const int t = threadIdx.x;
  __shared__ __align__(16) float qT[64][68];   // [d][s] padded
  __shared__ __align__(16) float kvl[64][64];  // [d][f]
  __shared__ __align__(16) float ksl[64];
  const int coff = h * DDIM;

  // stage q chunk transposed (bf16 -> f32)
  #pragma unroll
  for (int l = 0; l < 4; ++l) {
    const int idx  = t + l * 256;    // 0..1023 (4-elem slots)
    const int srow = idx >> 4;       // 0..63
    const int d4   = idx & 15;       // 0..15
    const int s = sc * 64 + srow;
    const int m = s * BATCH + b;
    const ushort4_t q4 = *(const ushort4_t*)&Qb[(size_t)m * CDIM + coff + d4 * 4];
    qT[d4 * 4 + 0][srow] = bf2f(q4[0]);
    qT[d4 * 4 + 1][srow] = bf2f(q4[1]);
    qT[d4 * 4 + 2][srow] = bf2f(q4[2]);
    qT[d4 * 4 + 3][srow] = bf2f(q4[3]);
  }
  const float* kvsrc = &kvm[(size_t)bh * 4096];
  #pragma unroll
  for (int l = 0; l < 4; ++l) {
    const int idx = t + l * 256;
    *(float4*)&kvl[0][idx * 4] = *(const float4*)&kvsrc[(size_t)idx * 4];
  }
  if (t < 16)
    *(float4*)&ksl[t * 4] = *(const float4*)&ksum[(size_t)bh * 64 + t * 4];
  __syncthreads();

  const int tr = t >> 4, tc = t & 15;
  float acc[4][4];
  #pragma unroll
  for (int i = 0; i < 4; ++i)
    #pragma unroll
    for (int j = 0; j < 4; ++j) acc[i][j] = 0.f;
  float dacc[4] = {0.f, 0.f, 0.f, 0.f};

  #pragma unroll 16
  for (int kk = 0; kk < 64; ++kk) {
    const float4 a  = *(const float4*)&qT[kk][tr * 4];
    const float4 bv = *(const float4*)&kvl[kk][tc * 4];
    const float ks = ksl[kk];
    const float av[4] = {a.x, a.y, a.z, a.w};
    const float bb[4] = {bv.x, bv.y, bv.z, bv.w};
    #pragma unroll
    for (int i = 0; i < 4; ++i) {
      dacc[i] = fmaf(av[i], ks, dacc[i]);
      #pragma unroll
      for (int j = 0; j < 4; ++j)
        acc[i][j] = fmaf(av[i], bb[j], acc[i][j]);
    }
  }

  #pragma unroll
  for (int i = 0; i < 4; ++i) {
    const int s = sc * 64 + tr * 4 + i;
    const int m = s * BATCH + b;
    const float inv = 1.f / (dacc[i] + EPS_F);
    ushort4_t o;
    o[0] = f2bf(acc[i][0] * inv); o[1] = f2bf(acc[i][1] * inv);
    o[2] = f2bf(acc[i][2] * inv); o[3] = f2bf(acc[i][3] * inv);
    *(ushort4_t*)&Qb[(size_t)m * CDIM + coff + tc * 4] = o;
  }
}

// ---------------------------------------------------------------------------
extern "C" void kernel_launch(void* const* d_in, const int* in_sizes, int n_in,
                              void* d_out, int out_size, void* d_ws, size_t ws_size,
                              hipStream_t stream) {
  const float* q_in = (const float*)d_in[0];
  const float* k_in = (const float*)d_in[1];
  const float* v_in = (const float*)d_in[2];
  const float* Wq   = (const float*)d_in[3];
  const float* bq   = (const float*)d_in[4];
  const float* Wk   = (const float*)d_in[5];
  const float* bk   = (const float*)d_in[6];
  const float* Wv   = (const float*)d_in[7];
  const float* bv   = (const float*)d_in[8];
  const float* Wp   = (const float*)d_in[9];
  const float* bp   = (const float*)d_in[10];
  float* out = (float*)d_out;

  const size_t NTOK = (size_t)MROWS * CDIM;            // 16,777,216 elems
  ushort_t* qbuf = (ushort_t*)d_ws;                    // bf16
  ushort_t* kbuf = qbuf + NTOK;
  ushort_t* vbuf = kbuf + NTOK;
  float* fbase    = (float*)(vbuf + NTOK);
  float* kvpart   = fbase;                             // 32*32*4096
  float* ksumpart = kvpart + (size_t)32 * 32 * 4096;   // 32*32*64
  float* kvm      = ksumpart + (size_t)32 * 32 * 64;   // 32*4096
  float* ksumm    = kvm + (size_t)32 * 4096;           // 32*64

  const dim3 blk(256);
  const dim3 gmm(MROWS / 128, CDIM / 128);             // (256, 4)

  // 1) Projections: fp32 X staged->bf16, bf16 MFMA, bf16 out (ELU+1 for Q,K)
  gemm_mfma<1, 0, 1><<<gmm, blk, 0, stream>>>(q_in, Wq, bq, qbuf);
  gemm_mfma<1, 0, 1><<<gmm, blk, 0, stream>>>(k_in, Wk, bk, kbuf);
  gemm_mfma<0, 0, 1><<<gmm, blk, 0, stream>>>(v_in, Wv, bv, vbuf);

  // 2) kv = sum_s k^T v ; ksum = sum_s k   (deterministic chunked)
  kv_partial<<<dim3(32, 32), blk, 0, stream>>>(kbuf, vbuf, kvpart, ksumpart);
  kv_reduce<<<dim3(32), blk, 0, stream>>>(kvpart, ksumpart, kvm, ksumm);

  // 3) y = (q @ kv) / (q . ksum + eps), bf16 in place over q buffer
  qkv_kernel<<<dim3(32, 128), blk, 0, stream>>>(qbuf, kvm, ksumm);

  // 4) Output projection: bf16 X direct, fp32 out -> d_out
  gemm_mfma<0, 1, 0><<<gmm, blk, 0, stream>>>(qbuf, Wp, bp, out);
}

// Round 3
// 282.873 us; speedup vs baseline: 3.4232x; 1.2945x over previous
//
#include <hip/hip_runtime.h>
#include <hip/hip_bf16.h>
#include <math.h>

// Problem constants: S=8192, B=4, C=512, H=8, D=64
#define S_LEN 8192
#define BATCH 4
#define CDIM  512
#define HEADS 8
#define DDIM  64
#define MROWS (S_LEN * BATCH)   // 32768 rows; row m = s*BATCH + b; layout [S,B,C]
#define EPS_F 1e-6f

typedef __attribute__((ext_vector_type(8))) short     short8_t;
typedef __attribute__((ext_vector_type(4))) float     f32x4;
typedef unsigned short ushort_t;
typedef __attribute__((ext_vector_type(8))) unsigned short ushort8_t;

static __device__ __forceinline__ ushort_t f2bf(float f) {
  __hip_bfloat16 h = __float2bfloat16(f);   // RNE
  return *(ushort_t*)&h;
}

// Async global->LDS, 16B per lane. LDS dest = wave-uniform base + lane*16.
static __device__ __forceinline__ void gl2lds16(const ushort_t* g, ushort_t* l) {
  __builtin_amdgcn_global_load_lds((const __attribute__((address_space(1))) void*)g,
                                   (__attribute__((address_space(3))) void*)l,
                                   16, 0, 0);
}

// ---------------------------------------------------------------------------
// fp32 -> bf16 conversion passes
// ---------------------------------------------------------------------------
__global__ __launch_bounds__(256)
void cvt3_kernel(const float* __restrict__ a, const float* __restrict__ b,
                 const float* __restrict__ c,
                 ushort_t* __restrict__ oa, ushort_t* __restrict__ ob,
                 ushort_t* __restrict__ oc) {
  const float* src = (blockIdx.y == 0) ? a : (blockIdx.y == 1) ? b : c;
  ushort_t* dst    = (blockIdx.y == 0) ? oa : (blockIdx.y == 1) ? ob : oc;
  const size_t i = ((size_t)blockIdx.x * 256 + threadIdx.x) * 8;
  const float4 x = *(const float4*)&src[i];
  const float4 y = *(const float4*)&src[i + 4];
  ushort8_t p;
  p[0] = f2bf(x.x); p[1] = f2bf(x.y); p[2] = f2bf(x.z); p[3] = f2bf(x.w);
  p[4] = f2bf(y.x); p[5] = f2bf(y.y); p[6] = f2bf(y.z); p[7] = f2bf(y.w);
  *(ushort8_t*)&dst[i] = p;
}

__global__ __launch_bounds__(256)
void cvtW_kernel(const float* __restrict__ a, const float* __restrict__ b,
                 const float* __restrict__ c, const float* __restrict__ d,
                 ushort_t* __restrict__ oa, ushort_t* __restrict__ ob,
                 ushort_t* __restrict__ oc, ushort_t* __restrict__ od) {
  const float* src = (blockIdx.y == 0) ? a : (blockIdx.y == 1) ? b :
                     (blockIdx.y == 2) ? c : d;
  ushort_t* dst    = (blockIdx.y == 0) ? oa : (blockIdx.y == 1) ? ob :
                     (blockIdx.y == 2) ? oc : od;
  const size_t i = ((size_t)blockIdx.x * 256 + threadIdx.x) * 8;
  const float4 x = *(const float4*)&src[i];
  const float4 y = *(const float4*)&src[i + 4];
  ushort8_t p;
  p[0] = f2bf(x.x); p[1] = f2bf(x.y); p[2] = f2bf(x.z); p[3] = f2bf(x.w);
  p[4] = f2bf(y.x); p[5] = f2bf(y.y); p[6] = f2bf(y.z); p[7] = f2bf(y.w);
  *(ushort8_t*)&dst[i] = p;
}

// ---------------------------------------------------------------------------
// Pure-bf16 MFMA GEMM (m97-style): Y[m][n] = act( sum_k A[m][k]*BT[n][k] + bias[n] )
// A:[M][512] bf16, BT:[512][512] bf16. BM=BN=128, BK=32, 256 thr, 4 waves 2x2,
// each wave 64x64 via 4x4 frags of 16x16x32. Staging: global_load_lds 16B into
// fragment-packed LDS (frag = 64 lanes x 16B contiguous): lane l of frag fm
// holds row fm*16+(l&15), k-slice (l>>4)*8.. -> conflict-free ds_read_b128.
// ---------------------------------------------------------------------------
template<int ACT, int OUTF32>
__global__ __launch_bounds__(256)
void gemm_bf16(const ushort_t* __restrict__ A, const ushort_t* __restrict__ BT,
               const float* __restrict__ bias, void* __restrict__ Yv) {
  __shared__ __align__(16) ushort_t alds[4096];   // 8 frags * 512 shorts
  __shared__ __align__(16) ushort_t blds[4096];
  const int t    = threadIdx.x;
  const int m0   = blockIdx.x * 128;
  const int n0   = blockIdx.y * 128;
  const int w    = t >> 6;
  const int lane = t & 63;
  const int wm   = (w >> 1) * 64;
  const int wn   = (w & 1) * 64;
  const int lr   = lane & 15;          // row-in-frag
  const int lk   = (lane >> 4) * 8;    // k-offset-in-frag

  f32x4 acc[4][4];
  #pragma unroll
  for (int mi = 0; mi < 4; ++mi)
    #pragma unroll
    for (int ni = 0; ni < 4; ++ni)
      acc[mi][ni] = (f32x4){0.f, 0.f, 0.f, 0.f};

  // per-lane global bases for this wave's two A-frags and two B-frags
  const ushort_t* ga0 = A  + (size_t)(m0 + w * 16 + lr) * CDIM + lk;
  const ushort_t* ga1 = A  + (size_t)(m0 + (w + 4) * 16 + lr) * CDIM + lk;
  const ushort_t* gb0 = BT + (size_t)(n0 + w * 16 + lr) * CDIM + lk;
  const ushort_t* gb1 = BT + (size_t)(n0 + (w + 4) * 16 + lr) * CDIM + lk;

  for (int kt = 0; kt < CDIM; kt += 32) {
    gl2lds16(ga0 + kt, &alds[(w)     * 512]);
    gl2lds16(ga1 + kt, &alds[(w + 4) * 512]);
    gl2lds16(gb0 + kt, &blds[(w)     * 512]);
    gl2lds16(gb1 + kt, &blds[(w + 4) * 512]);
    __syncthreads();   // drains vmcnt -> LDS filled for all waves

    short8_t af[4], bfr[4];
    #pragma unroll
    for (int mi = 0; mi < 4; ++mi)
      af[mi] = *(const short8_t*)&alds[((wm >> 4) + mi) * 512 + lane * 8];
    #pragma unroll
    for (int ni = 0; ni < 4; ++ni)
      bfr[ni] = *(const short8_t*)&blds[((wn >> 4) + ni) * 512 + lane * 8];
    #pragma unroll
    for (int mi = 0; mi < 4; ++mi)
      #pragma unroll
      for (int ni = 0; ni < 4; ++ni)
        acc[mi][ni] = __builtin_amdgcn_mfma_f32_16x16x32_bf16(
            af[mi], bfr[ni], acc[mi][ni], 0, 0, 0);
    __syncthreads();   // all reads done before next tile's DMA overwrites
  }

  // epilogue: C layout col=lane&15, row=(lane>>4)*4+r  (verified r2)
  float* Yf = (float*)Yv;
  ushort_t* Yh = (ushort_t*)Yv;
  float bi[4];
  int coln[4];
  #pragma unroll
  for (int ni = 0; ni < 4; ++ni) {
    coln[ni] = n0 + wn + ni * 16 + lr;
    bi[ni]   = bias[coln[ni]];
  }
  #pragma unroll
  for (int mi = 0; mi < 4; ++mi) {
    #pragma unroll
    for (int r = 0; r < 4; ++r) {
      const int m = m0 + wm + mi * 16 + (lane >> 4) * 4 + r;
      #pragma unroll
      for (int ni = 0; ni < 4; ++ni) {
        float v = acc[mi][ni][r] + bi[ni];
        if (ACT) v = (v > 0.f) ? (v + 1.f) : expf(v);
        const size_t o = (size_t)m * CDIM + coln[ni];
        if (OUTF32) Yf[o] = v;
        else        Yh[o] = f2bf(v);
      }
    }
  }
}

// ---------------------------------------------------------------------------
// kv GEMM: per (b,h), kv[d][f] = sum_s k[s][d]*v[s][f], ksum[d] = sum_s k[s][d].
// Split-K: grid (32 bh, 16 chunks of 512 s). Reg-staged transpose into
// fragment-packed LDS (A = k^T, B = v); ksum via ones-B-fragment MFMA.
// ---------------------------------------------------------------------------
__global__ __launch_bounds__(256)
void gemm_kv(const ushort_t* __restrict__ Kb, const ushort_t* __restrict__ Vb,
             float* __restrict__ kvpart, float* __restrict__ ksumpart) {
  __shared__ __align__(16) ushort_t klds[8192];  // [sb][dg][lane][8]
  __shared__ __align__(16) ushort_t vlds[8192];
  const int bh    = blockIdx.x;        // 0..31
  const int chunk = blockIdx.y;        // 0..15 (512 s each)
  const int b = bh >> 3, h = bh & 7;
  const int t = threadIdx.x;
  const int w = t >> 6;
  const int lane = t & 63;

  f32x4 acc[4];
  #pragma unroll
  for (int fg = 0; fg < 4; ++fg) acc[fg] = (f32x4){0.f, 0.f, 0.f, 0.f};
  f32x4 accs = (f32x4){0.f, 0.f, 0.f, 0.f};

  short8_t ones;
  #pragma unroll
  for (int i = 0; i < 8; ++i) ones[i] = (short)0x3F80;   // bf16 1.0

  for (int round = 0; round < 4; ++round) {
    const int sbase = chunk * 512 + round * 128;
    __syncthreads();   // prev compute done before overwriting LDS
    // stage 128 s-rows of k and v, transposed into fragment-packed layout
    #pragma unroll
    for (int i = 0; i < 4; ++i) {
      const int idx  = i * 256 + t;    // 0..1023 packets
      const int sl   = idx >> 3;       // 0..127
      const int d8   = idx & 7;        // 8-col group
      const size_t src = (size_t)((sbase + sl) * BATCH + b) * CDIM + h * DDIM + d8 * 8;
      const ushort8_t kp = *(const ushort8_t*)&Kb[src];
      const ushort8_t vp = *(const ushort8_t*)&Vb[src];
      const int sb  = sl >> 5;
      const int j   = sl & 7;
      const int lp0 = (d8 & 1) * 8 + ((sl >> 3) & 3) * 16;
      const int dg  = d8 >> 1;
      const int kbase = ((sb * 4 + dg) * 64 + lp0) * 8 + j;
      #pragma unroll
      for (int e = 0; e < 8; ++e) {
        klds[kbase + e * 8] = kp[e];
        vlds[kbase + e * 8] = vp[e];
      }
    }
    __syncthreads();
    // compute: wave w owns d-group w
    #pragma unroll
    for (int sb = 0; sb < 4; ++sb) {
      const short8_t af = *(const short8_t*)&klds[((sb * 4 + w) * 64 + lane) * 8];
      accs = __builtin_amdgcn_mfma_f32_16x16x32_bf16(af, ones, accs, 0, 0, 0);
      #pragma unroll
      for (int fg = 0; fg < 4; ++fg) {
        const short8_t bf = *(const short8_t*)&vlds[((sb * 4 + fg) * 64 + lane) * 8];
        acc[fg] = __builtin_amdgcn_mfma_f32_16x16x32_bf16(af, bf, acc[fg], 0, 0, 0);
      }
    }
  }

  // write partials: d = w*16 + (lane>>4)*4 + r, f = fg*16 + (lane&15)
  const size_t obase = ((size_t)bh * 16 + chunk) * 64;
  #pragma unroll
  for (int fg = 0; fg < 4; ++fg)
    #pragma unroll
    for (int r = 0; r < 4; ++r) {
      const int d = w * 16 + (lane >> 4) * 4 + r;
      kvpart[(obase + d) * 64 + fg * 16 + (lane & 15)] = acc[fg][r];
    }
  if ((lane & 15) == 0) {
    #pragma unroll
    for (int r = 0; r < 4; ++r)
      ksumpart[obase + w * 16 + (lane >> 4) * 4 + r] = accs[r];
  }
}

// ---------------------------------------------------------------------------
// Reduce split-K partials; emit kvT_pad bf16 [bh][80][64]:
// rows 0..63 = kv^T (row f, col d), row 64 = ksum, rows 65..79 = 0.
// ---------------------------------------------------------------------------
__global__ __launch_bounds__(256)
void kv_finish(const float* __restrict__ kvpart, const float* __restrict__ ksumpart,
               ushort_t* __restrict__ kvT) {
  const int bh = blockIdx.x;
  const int t  = threadIdx.x;
  for (int idx = t; idx < 4096; idx += 256) {
    const int d = idx >> 6, f = idx & 63;
    float s = 0.f;
    for (int c = 0; c < 16; ++c)
      s += kvpart[(((size_t)bh * 16 + c) * 64 + d) * 64 + f];
    kvT[((size_t)bh * 80 + f) * 64 + d] = f2bf(s);
  }
  if (t < 64) {
    float s = 0.f;
    for (int c = 0; c < 16; ++c)
      s += ksumpart[((size_t)bh * 16 + c) * 64 + t];
    kvT[((size_t)bh * 80 + 64) * 64 + t] = f2bf(s);
  }
  for (int i = t; i < 15 * 64; i += 256)
    kvT[((size_t)bh * 80 + 65) * 64 + i] = 0;
}

// ---------------------------------------------------------------------------
// qkv GEMM: y[s][f] = (sum_d q[s][d]*kv[d][f]) / (sum_d q[s][d]*ksum[d] + EPS)
// A = q rows (gathered, m = s*4+b), BT = kvT_pad [80][64]. N=80: col 64 = denom.
// M-tile 128 s-rows; K=64 (2 steps). Writes y bf16 in place over q region.
// ---------------------------------------------------------------------------
__global__ __launch_bounds__(256)
void gemm_qkv(ushort_t* __restrict__ Qb, const ushort_t* __restrict__ kvT) {
  __shared__ __align__(16) ushort_t alds[8192];   // [ks][fm] 2*8 frags
  __shared__ __align__(16) ushort_t blds[5120];   // [ks][fg] 2*5 frags
  const int bh    = blockIdx.x;   // 0..31
  const int chunk = blockIdx.y;   // 0..63 (128 s each)
  const int b = bh >> 3, h = bh & 7;
  const int t = threadIdx.x;
  const int w = t >> 6;
  const int lane = t & 63;
  const int lr = lane & 15;
  const int lk = (lane >> 4) * 8;

  // stage A: 16 frags (ks 0..1, fm 0..7); wave w issues 4
  #pragma unroll
  for (int i = 0; i < 4; ++i) {
    const int fidx = w * 4 + i;
    const int ks = fidx >> 3, fm = fidx & 7;
    const ushort_t* src = Qb +
        (size_t)((chunk * 128 + fm * 16 + lr) * BATCH + b) * CDIM +
        h * DDIM + ks * 32 + lk;
    gl2lds16(src, &alds[fidx * 512]);
  }
  // stage B: 10 frags (ks 0..1, fg 0..4)
  for (int idx = w; idx < 10; idx += 4) {
    const int ks = idx / 5, fg = idx % 5;
    const ushort_t* src = kvT + (size_t)(bh * 80 + fg * 16 + lr) * 64 + ks * 32 + lk;
    gl2lds16(src, &blds[idx * 512]);
  }
  __syncthreads();

  f32x4 acc[2][5];
  #pragma unroll
  for (int mi = 0; mi < 2; ++mi)
    #pragma unroll
    for (int fg = 0; fg < 5; ++fg)
      acc[mi][fg] = (f32x4){0.f, 0.f, 0.f, 0.f};

  #pragma unroll
  for (int ks = 0; ks < 2; ++ks) {
    short8_t af[2], bf[5];
    #pragma unroll
    for (int mi = 0; mi < 2; ++mi)
      af[mi] = *(const short8_t*)&alds[(ks * 8 + w * 2 + mi) * 512 + lane * 8];
    #pragma unroll
    for (int fg = 0; fg < 5; ++fg)
      bf[fg] = *(const short8_t*)&blds[(ks * 5 + fg) * 512 + lane * 8];
    #pragma unroll
    for (int mi = 0; mi < 2; ++mi)
      #pragma unroll
      for (int fg = 0; fg < 5; ++fg)
        acc[mi][fg] = __builtin_amdgcn_mfma_f32_16x16x32_bf16(
            af[mi], bf[fg], acc[mi][fg], 0, 0, 0);
  }

  // epilogue: denom = col 64 (fg=4, col-in-frag 0) broadcast within 16-group
  #pragma unroll
  for (int mi = 0; mi < 2; ++mi) {
    #pragma unroll
    for (int r = 0; r < 4; ++r) {
      const float dv  = __shfl(acc[mi][4][r], lane & 48);
      const float inv = 1.f / (dv + EPS_F);
      const int s = chunk * 128 + w * 32 + mi * 16 + (lane >> 4) * 4 + r;
      const size_t rowb = (size_t)(s * BATCH + b) * CDIM + h * DDIM;
      #pragma unroll
      for (int fg = 0; fg < 4; ++fg)
        Qb[rowb + fg * 16 + lr] = f2bf(acc[mi][fg][r] * inv);
    }
  }
}

// ---------------------------------------------------------------------------
extern "C" void kernel_launch(void* const* d_in, const int* in_sizes, int n_in,
                              void* d_out, int out_size, void* d_ws, size_t ws_size,
                              hipStream_t stream) {
  const float* q_in = (const float*)d_in[0];
  const float* k_in = (const float*)d_in[1];
  const float* v_in = (const float*)d_in[2];
  const float* Wq   = (const float*)d_in[3];
  const float* bq   = (const float*)d_in[4];
  const float* Wk   = (const float*)d_in[5];
  const float* bk   = (const float*)d_in[6];
  const float* Wv   = (const float*)d_in[7];
  const float* bv   = (const float*)d_in[8];
  const float* Wp   = (const float*)d_in[9];
  const float* bp   = (const float*)d_in[10];
  float* out = (float*)d_out;

  const size_t NTOK = (size_t)MROWS * CDIM;      // 16,777,216 elems
  const size_t NW   = (size_t)CDIM * CDIM;       // 262,144
  ushort_t* qin_bf = (ushort_t*)d_ws;
  ushort_t* kin_bf = qin_bf + NTOK;
  ushort_t* vin_bf = kin_bf + NTOK;
  ushort_t* Wq_bf  = vin_bf + NTOK;
  ushort_t* Wk_bf  = Wq_bf + NW;
  ushort_t* Wv_bf  = Wk_bf + NW;
  ushort_t* Wp_bf  = Wv_bf + NW;
  ushort_t* qbuf   = Wp_bf + NW;
  ushort_t* kbuf   = qbuf + NTOK;
  ushort_t* vbuf   = kbuf + NTOK;
  ushort_t* kvT    = vbuf + NTOK;                       // 32*80*64
  float* kvpart    = (float*)(kvT + (size_t)32 * 80 * 64);  // 512*64*64
  float* ksumpart  = kvpart + (size_t)512 * 64 * 64;        // 512*64

  const dim3 blk(256);

  // 1) fp32 -> bf16
  cvt3_kernel<<<dim3(8192, 3), blk, 0, stream>>>(q_in, k_in, v_in,
                                                 qin_bf, kin_bf, vin_bf);
  cvtW_kernel<<<dim3(128, 4), blk, 0, stream>>>(Wq, Wk, Wv, Wp,
                                                Wq_bf, Wk_bf, Wv_bf, Wp_bf);

  // 2) Projections (ELU+1 fused for Q,K), bf16 out
  const dim3 gmm(MROWS / 128, CDIM / 128);   // (256, 4)
  gemm_bf16<1, 0><<<gmm, blk, 0, stream>>>(qin_bf, Wq_bf, bq, qbuf);
  gemm_bf16<1, 0><<<gmm, blk, 0, stream>>>(kin_bf, Wk_bf, bk, kbuf);
  gemm_bf16<0, 0><<<gmm, blk, 0, stream>>>(vin_bf, Wv_bf, bv, vbuf);

  // 3) kv = sum_s k^T v (+ ksum via ones-MFMA), split-K then finish
  gemm_kv<<<dim3(32, 16), blk, 0, stream>>>(kbuf, vbuf, kvpart, ksumpart);
  kv_finish<<<dim3(32), blk, 0, stream>>>(kvpart, ksumpart, kvT);

  // 4) y = (q @ kv) / (q . ksum + eps), bf16 in place over q buffer
  gemm_qkv<<<dim3(32, 64), blk, 0, stream>>>(qbuf, kvT);

  // 5) Output projection -> fp32 d_out
  gemm_bf16<0, 1><<<gmm, blk, 0, stream>>>(qbuf, Wp_bf, bp, out);
}

// Round 4
// 273.126 us; speedup vs baseline: 3.5453x; 1.0357x over previous
//
#include <hip/hip_runtime.h>
#include <hip/hip_bf16.h>
#include <math.h>

// Problem constants: S=8192, B=4, C=512, H=8, D=64
#define S_LEN 8192
#define BATCH 4
#define CDIM  512
#define HEADS 8
#define DDIM  64
#define MROWS (S_LEN * BATCH)   // 32768 rows; row m = s*BATCH + b; layout [S,B,C]
#define EPS_F 1e-6f

typedef __attribute__((ext_vector_type(8))) short     short8_t;
typedef __attribute__((ext_vector_type(4))) float     f32x4;
typedef unsigned short ushort_t;
typedef __attribute__((ext_vector_type(4))) unsigned short ushort4_t;
typedef __attribute__((ext_vector_type(8))) unsigned short ushort8_t;

static __device__ __forceinline__ ushort_t f2bf(float f) {
  __hip_bfloat16 h = __float2bfloat16(f);   // RNE
  return *(ushort_t*)&h;
}

// Async global->LDS, 16B per lane. LDS dest = wave-uniform base + lane*16.
static __device__ __forceinline__ void gl2lds16(const ushort_t* g, ushort_t* l) {
  __builtin_amdgcn_global_load_lds((const __attribute__((address_space(1))) void*)g,
                                   (__attribute__((address_space(3))) void*)l,
                                   16, 0, 0);
}

// ---------------------------------------------------------------------------
// Weights fp32 -> bf16 (4 MB total, ~3 us)
// ---------------------------------------------------------------------------
__global__ __launch_bounds__(256)
void cvtW_kernel(const float* __restrict__ a, const float* __restrict__ b,
                 const float* __restrict__ c, const float* __restrict__ d,
                 ushort_t* __restrict__ oa, ushort_t* __restrict__ ob,
                 ushort_t* __restrict__ oc, ushort_t* __restrict__ od) {
  const float* src = (blockIdx.y == 0) ? a : (blockIdx.y == 1) ? b :
                     (blockIdx.y == 2) ? c : d;
  ushort_t* dst    = (blockIdx.y == 0) ? oa : (blockIdx.y == 1) ? ob :
                     (blockIdx.y == 2) ? oc : od;
  const size_t i = ((size_t)blockIdx.x * 256 + threadIdx.x) * 8;
  const float4 x = *(const float4*)&src[i];
  const float4 y = *(const float4*)&src[i + 4];
  ushort8_t p;
  p[0] = f2bf(x.x); p[1] = f2bf(x.y); p[2] = f2bf(x.z); p[3] = f2bf(x.w);
  p[4] = f2bf(y.x); p[5] = f2bf(y.y); p[6] = f2bf(y.z); p[7] = f2bf(y.w);
  *(ushort8_t*)&dst[i] = p;
}

// ---------------------------------------------------------------------------
// Fused projection GEMM: Y[m][n] = act( sum_k X[m][k]*W[n][k] + bias[n] )
// X fp32 [M][512] (converted to bf16 while staging, reg->ds_write path,
// layout verified r2). W bf16 [512][512] via global_load_lds (verified r3).
// BM=BN=128, BK=32, 256 thr, 4 waves 2x2, wave=64x64 via 4x4 16x16x32 frags.
// Output bf16, optional ELU(x)+1.
// ---------------------------------------------------------------------------
template<int ACT>
__global__ __launch_bounds__(256)
void gemm_projA(const float* __restrict__ X, const ushort_t* __restrict__ BT,
                const float* __restrict__ bias, ushort_t* __restrict__ Y) {
  __shared__ __align__(16) ushort_t alds[4096];   // 8 frags * 512 shorts
  __shared__ __align__(16) ushort_t blds[4096];
  const int t    = threadIdx.x;
  const int m0   = blockIdx.x * 128;
  const int n0   = blockIdx.y * 128;
  const int w    = t >> 6;
  const int lane = t & 63;
  const int wm   = (w >> 1) * 64;
  const int wn   = (w & 1) * 64;
  const int lr   = lane & 15;
  const int lk   = (lane >> 4) * 8;

  // A staging map (round-2 verified): packet p = i*256+t ->
  // fm=p>>7, lp=(p>>1)&63, half=p&1; row=fm*16+(lp&15), k=(lp>>4 &3)*8+half*4
  int row_a[4], kloc[4], ldsp[4];
  #pragma unroll
  for (int i = 0; i < 4; ++i) {
    const int p  = i * 256 + t;
    const int fm = p >> 7;
    const int lp = (p >> 1) & 63;
    row_a[i] = fm * 16 + (lp & 15);
    kloc[i]  = ((lp >> 4) & 3) * 8 + (p & 1) * 4;
    ldsp[i]  = p * 4;
  }

  f32x4 acc[4][4];
  #pragma unroll
  for (int mi = 0; mi < 4; ++mi)
    #pragma unroll
    for (int ni = 0; ni < 4; ++ni)
      acc[mi][ni] = (f32x4){0.f, 0.f, 0.f, 0.f};

  // per-lane global bases for this wave's two B-frags (DMA path)
  const ushort_t* gb0 = BT + (size_t)(n0 + w * 16 + lr) * CDIM + lk;
  const ushort_t* gb1 = BT + (size_t)(n0 + (w + 4) * 16 + lr) * CDIM + lk;

  for (int kt = 0; kt < CDIM; kt += 32) {
    // A fp32 loads for this K-step
    float4 axf[4];
    #pragma unroll
    for (int i = 0; i < 4; ++i)
      axf[i] = *(const float4*)&X[(size_t)(m0 + row_a[i]) * CDIM + kt + kloc[i]];
    __syncthreads();   // previous tile fully consumed
    // convert + ds_write A; DMA B
    #pragma unroll
    for (int i = 0; i < 4; ++i) {
      ushort4_t pa;
      pa[0] = f2bf(axf[i].x); pa[1] = f2bf(axf[i].y);
      pa[2] = f2bf(axf[i].z); pa[3] = f2bf(axf[i].w);
      *(ushort4_t*)&alds[ldsp[i]] = pa;
    }
    gl2lds16(gb0 + kt, &blds[(w)     * 512]);
    gl2lds16(gb1 + kt, &blds[(w + 4) * 512]);
    __syncthreads();   // ds_write (lgkm) + DMA (vm) drained for all waves

    short8_t af[4], bfr[4];
    #pragma unroll
    for (int mi = 0; mi < 4; ++mi)
      af[mi] = *(const short8_t*)&alds[((wm >> 4) + mi) * 512 + lane * 8];
    #pragma unroll
    for (int ni = 0; ni < 4; ++ni)
      bfr[ni] = *(const short8_t*)&blds[((wn >> 4) + ni) * 512 + lane * 8];
    #pragma unroll
    for (int mi = 0; mi < 4; ++mi)
      #pragma unroll
      for (int ni = 0; ni < 4; ++ni)
        acc[mi][ni] = __builtin_amdgcn_mfma_f32_16x16x32_bf16(
            af[mi], bfr[ni], acc[mi][ni], 0, 0, 0);
  }

  // epilogue: C layout col=lane&15, row=(lane>>4)*4+r
  float bi[4];
  int coln[4];
  #pragma unroll
  for (int ni = 0; ni < 4; ++ni) {
    coln[ni] = n0 + wn + ni * 16 + lr;
    bi[ni]   = bias[coln[ni]];
  }
  #pragma unroll
  for (int mi = 0; mi < 4; ++mi) {
    #pragma unroll
    for (int r = 0; r < 4; ++r) {
      const int m = m0 + wm + mi * 16 + (lane >> 4) * 4 + r;
      #pragma unroll
      for (int ni = 0; ni < 4; ++ni) {
        float v = acc[mi][ni][r] + bi[ni];
        if (ACT) v = (v > 0.f) ? (v + 1.f) : expf(v);
        Y[(size_t)m * CDIM + coln[ni]] = f2bf(v);
      }
    }
  }
}

// ---------------------------------------------------------------------------
// Pure-bf16 MFMA GEMM (round-3 verified): used for the output projection.
// ---------------------------------------------------------------------------
template<int ACT, int OUTF32>
__global__ __launch_bounds__(256)
void gemm_bf16(const ushort_t* __restrict__ A, const ushort_t* __restrict__ BT,
               const float* __restrict__ bias, void* __restrict__ Yv) {
  __shared__ __align__(16) ushort_t alds[4096];
  __shared__ __align__(16) ushort_t blds[4096];
  const int t    = threadIdx.x;
  const int m0   = blockIdx.x * 128;
  const int n0   = blockIdx.y * 128;
  const int w    = t >> 6;
  const int lane = t & 63;
  const int wm   = (w >> 1) * 64;
  const int wn   = (w & 1) * 64;
  const int lr   = lane & 15;
  const int lk   = (lane >> 4) * 8;

  f32x4 acc[4][4];
  #pragma unroll
  for (int mi = 0; mi < 4; ++mi)
    #pragma unroll
    for (int ni = 0; ni < 4; ++ni)
      acc[mi][ni] = (f32x4){0.f, 0.f, 0.f, 0.f};

  const ushort_t* ga0 = A  + (size_t)(m0 + w * 16 + lr) * CDIM + lk;
  const ushort_t* ga1 = A  + (size_t)(m0 + (w + 4) * 16 + lr) * CDIM + lk;
  const ushort_t* gb0 = BT + (size_t)(n0 + w * 16 + lr) * CDIM + lk;
  const ushort_t* gb1 = BT + (size_t)(n0 + (w + 4) * 16 + lr) * CDIM + lk;

  for (int kt = 0; kt < CDIM; kt += 32) {
    gl2lds16(ga0 + kt, &alds[(w)     * 512]);
    gl2lds16(ga1 + kt, &alds[(w + 4) * 512]);
    gl2lds16(gb0 + kt, &blds[(w)     * 512]);
    gl2lds16(gb1 + kt, &blds[(w + 4) * 512]);
    __syncthreads();

    short8_t af[4], bfr[4];
    #pragma unroll
    for (int mi = 0; mi < 4; ++mi)
      af[mi] = *(const short8_t*)&alds[((wm >> 4) + mi) * 512 + lane * 8];
    #pragma unroll
    for (int ni = 0; ni < 4; ++ni)
      bfr[ni] = *(const short8_t*)&blds[((wn >> 4) + ni) * 512 + lane * 8];
    #pragma unroll
    for (int mi = 0; mi < 4; ++mi)
      #pragma unroll
      for (int ni = 0; ni < 4; ++ni)
        acc[mi][ni] = __builtin_amdgcn_mfma_f32_16x16x32_bf16(
            af[mi], bfr[ni], acc[mi][ni], 0, 0, 0);
    __syncthreads();
  }

  float* Yf = (float*)Yv;
  ushort_t* Yh = (ushort_t*)Yv;
  float bi[4];
  int coln[4];
  #pragma unroll
  for (int ni = 0; ni < 4; ++ni) {
    coln[ni] = n0 + wn + ni * 16 + lr;
    bi[ni]   = bias[coln[ni]];
  }
  #pragma unroll
  for (int mi = 0; mi < 4; ++mi) {
    #pragma unroll
    for (int r = 0; r < 4; ++r) {
      const int m = m0 + wm + mi * 16 + (lane >> 4) * 4 + r;
      #pragma unroll
      for (int ni = 0; ni < 4; ++ni) {
        float v = acc[mi][ni][r] + bi[ni];
        if (ACT) v = (v > 0.f) ? (v + 1.f) : expf(v);
        const size_t o = (size_t)m * CDIM + coln[ni];
        if (OUTF32) Yf[o] = v;
        else        Yh[o] = f2bf(v);
      }
    }
  }
}

// ---------------------------------------------------------------------------
// kv GEMM: per (b,h), kv[d][f] = sum_s k[s][d]*v[s][f], ksum[d] = sum_s k[s][d].
// Split-K: grid (32 bh, 16 chunks of 512 s). Reg-staged transpose into
// fragment-packed LDS (A = k^T, B = v); ksum via ones-B-fragment MFMA.
// ---------------------------------------------------------------------------
__global__ __launch_bounds__(256)
void gemm_kv(const ushort_t* __restrict__ Kb, const ushort_t* __restrict__ Vb,
             float* __restrict__ kvpart, float* __restrict__ ksumpart) {
  __shared__ __align__(16) ushort_t klds[8192];
  __shared__ __align__(16) ushort_t vlds[8192];
  const int bh    = blockIdx.x;
  const int chunk = blockIdx.y;
  const int b = bh >> 3, h = bh & 7;
  const int t = threadIdx.x;
  const int w = t >> 6;
  const int lane = t & 63;

  f32x4 acc[4];
  #pragma unroll
  for (int fg = 0; fg < 4; ++fg) acc[fg] = (f32x4){0.f, 0.f, 0.f, 0.f};
  f32x4 accs = (f32x4){0.f, 0.f, 0.f, 0.f};

  short8_t ones;
  #pragma unroll
  for (int i = 0; i < 8; ++i) ones[i] = (short)0x3F80;

  for (int round = 0; round < 4; ++round) {
    const int sbase = chunk * 512 + round * 128;
    __syncthreads();
    #pragma unroll
    for (int i = 0; i < 4; ++i) {
      const int idx  = i * 256 + t;
      const int sl   = idx >> 3;
      const int d8   = idx & 7;
      const size_t src = (size_t)((sbase + sl) * BATCH + b) * CDIM + h * DDIM + d8 * 8;
      const ushort8_t kp = *(const ushort8_t*)&Kb[src];
      const ushort8_t vp = *(const ushort8_t*)&Vb[src];
      const int sb  = sl >> 5;
      const int j   = sl & 7;
      const int lp0 = (d8 & 1) * 8 + ((sl >> 3) & 3) * 16;
      const int dg  = d8 >> 1;
      const int kbase = ((sb * 4 + dg) * 64 + lp0) * 8 + j;
      #pragma unroll
      for (int e = 0; e < 8; ++e) {
        klds[kbase + e * 8] = kp[e];
        vlds[kbase + e * 8] = vp[e];
      }
    }
    __syncthreads();
    #pragma unroll
    for (int sb = 0; sb < 4; ++sb) {
      const short8_t af = *(const short8_t*)&klds[((sb * 4 + w) * 64 + lane) * 8];
      accs = __builtin_amdgcn_mfma_f32_16x16x32_bf16(af, ones, accs, 0, 0, 0);
      #pragma unroll
      for (int fg = 0; fg < 4; ++fg) {
        const short8_t bf = *(const short8_t*)&vlds[((sb * 4 + fg) * 64 + lane) * 8];
        acc[fg] = __builtin_amdgcn_mfma_f32_16x16x32_bf16(af, bf, acc[fg], 0, 0, 0);
      }
    }
  }

  const size_t obase = ((size_t)bh * 16 + chunk) * 64;
  #pragma unroll
  for (int fg = 0; fg < 4; ++fg)
    #pragma unroll
    for (int r = 0; r < 4; ++r) {
      const int d = w * 16 + (lane >> 4) * 4 + r;
      kvpart[(obase + d) * 64 + fg * 16 + (lane & 15)] = acc[fg][r];
    }
  if ((lane & 15) == 0) {
    #pragma unroll
    for (int r = 0; r < 4; ++r)
      ksumpart[obase + w * 16 + (lane >> 4) * 4 + r] = accs[r];
  }
}

// ---------------------------------------------------------------------------
__global__ __launch_bounds__(256)
void kv_finish(const float* __restrict__ kvpart, const float* __restrict__ ksumpart,
               ushort_t* __restrict__ kvT) {
  const int bh = blockIdx.x;
  const int t  = threadIdx.x;
  for (int idx = t; idx < 4096; idx += 256) {
    const int d = idx >> 6, f = idx & 63;
    float s = 0.f;
    for (int c = 0; c < 16; ++c)
      s += kvpart[(((size_t)bh * 16 + c) * 64 + d) * 64 + f];
    kvT[((size_t)bh * 80 + f) * 64 + d] = f2bf(s);
  }
  if (t < 64) {
    float s = 0.f;
    for (int c = 0; c < 16; ++c)
      s += ksumpart[((size_t)bh * 16 + c) * 64 + t];
    kvT[((size_t)bh * 80 + 64) * 64 + t] = f2bf(s);
  }
  for (int i = t; i < 15 * 64; i += 256)
    kvT[((size_t)bh * 80 + 65) * 64 + i] = 0;
}

// ---------------------------------------------------------------------------
// qkv GEMM: y = (q @ kv) / (q . ksum + eps); B = kvT_pad [80][64], col 64 = denom.
// ---------------------------------------------------------------------------
__global__ __launch_bounds__(256)
void gemm_qkv(ushort_t* __restrict__ Qb, const ushort_t* __restrict__ kvT) {
  __shared__ __align__(16) ushort_t alds[8192];
  __shared__ __align__(16) ushort_t blds[5120];
  const int bh    = blockIdx.x;
  const int chunk = blockIdx.y;
  const int b = bh >> 3, h = bh & 7;
  const int t = threadIdx.x;
  const int w = t >> 6;
  const int lane = t & 63;
  const int lr = lane & 15;
  const int lk = (lane >> 4) * 8;

  #pragma unroll
  for (int i = 0; i < 4; ++i) {
    const int fidx = w * 4 + i;
    const int ks = fidx >> 3, fm = fidx & 7;
    const ushort_t* src = Qb +
        (size_t)((chunk * 128 + fm * 16 + lr) * BATCH + b) * CDIM +
        h * DDIM + ks * 32 + lk;
    gl2lds16(src, &alds[fidx * 512]);
  }
  for (int idx = w; idx < 10; idx += 4) {
    const int ks = idx / 5, fg = idx % 5;
    const ushort_t* src = kvT + (size_t)(bh * 80 + fg * 16 + lr) * 64 + ks * 32 + lk;
    gl2lds16(src, &blds[idx * 512]);
  }
  __syncthreads();

  f32x4 acc[2][5];
  #pragma unroll
  for (int mi = 0; mi < 2; ++mi)
    #pragma unroll
    for (int fg = 0; fg < 5; ++fg)
      acc[mi][fg] = (f32x4){0.f, 0.f, 0.f, 0.f};

  #pragma unroll
  for (int ks = 0; ks < 2; ++ks) {
    short8_t af[2], bf[5];
    #pragma unroll
    for (int mi = 0; mi < 2; ++mi)
      af[mi] = *(const short8_t*)&alds[(ks * 8 + w * 2 + mi) * 512 + lane * 8];
    #pragma unroll
    for (int fg = 0; fg < 5; ++fg)
      bf[fg] = *(const short8_t*)&blds[(ks * 5 + fg) * 512 + lane * 8];
    #pragma unroll
    for (int mi = 0; mi < 2; ++mi)
      #pragma unroll
      for (int fg = 0; fg < 5; ++fg)
        acc[mi][fg] = __builtin_amdgcn_mfma_f32_16x16x32_bf16(
            af[mi], bf[fg], acc[mi][fg], 0, 0, 0);
  }

  #pragma unroll
  for (int mi = 0; mi < 2; ++mi) {
    #pragma unroll
    for (int r = 0; r < 4; ++r) {
      const float dv  = __shfl(acc[mi][4][r], lane & 48);
      const float inv = 1.f / (dv + EPS_F);
      const int s = chunk * 128 + w * 32 + mi * 16 + (lane >> 4) * 4 + r;
      const size_t rowb = (size_t)(s * BATCH + b) * CDIM + h * DDIM;
      #pragma unroll
      for (int fg = 0; fg < 4; ++fg)
        Qb[rowb + fg * 16 + lr] = f2bf(acc[mi][fg][r] * inv);
    }
  }
}

// ---------------------------------------------------------------------------
extern "C" void kernel_launch(void* const* d_in, const int* in_sizes, int n_in,
                              void* d_out, int out_size, void* d_ws, size_t ws_size,
                              hipStream_t stream) {
  const float* q_in = (const float*)d_in[0];
  const float* k_in = (const float*)d_in[1];
  const float* v_in = (const float*)d_in[2];
  const float* Wq   = (const float*)d_in[3];
  const float* bq   = (const float*)d_in[4];
  const float* Wk   = (const float*)d_in[5];
  const float* bk   = (const float*)d_in[6];
  const float* Wv   = (const float*)d_in[7];
  const float* bv   = (const float*)d_in[8];
  const float* Wp   = (const float*)d_in[9];
  const float* bp   = (const float*)d_in[10];
  float* out = (float*)d_out;

  const size_t NTOK = (size_t)MROWS * CDIM;      // 16,777,216 elems
  const size_t NW   = (size_t)CDIM * CDIM;       // 262,144
  ushort_t* Wq_bf  = (ushort_t*)d_ws;
  ushort_t* Wk_bf  = Wq_bf + NW;
  ushort_t* Wv_bf  = Wk_bf + NW;
  ushort_t* Wp_bf  = Wv_bf + NW;
  ushort_t* qbuf   = Wp_bf + NW;
  ushort_t* kbuf   = qbuf + NTOK;
  ushort_t* vbuf   = kbuf + NTOK;
  ushort_t* kvT    = vbuf + NTOK;                           // 32*80*64
  float* kvpart    = (float*)(kvT + (size_t)32 * 80 * 64);  // 512*64*64
  float* ksumpart  = kvpart + (size_t)512 * 64 * 64;        // 512*64

  const dim3 blk(256);

  // 1) Weights fp32 -> bf16 (inputs stay fp32; converted inside proj GEMMs)
  cvtW_kernel<<<dim3(128, 4), blk, 0, stream>>>(Wq, Wk, Wv, Wp,
                                                Wq_bf, Wk_bf, Wv_bf, Wp_bf);

  // 2) Fused projections (fp32 A -> bf16 staging; ELU+1 for Q,K), bf16 out
  const dim3 gmm(MROWS / 128, CDIM / 128);   // (256, 4)
  gemm_projA<1><<<gmm, blk, 0, stream>>>(q_in, Wq_bf, bq, qbuf);
  gemm_projA<1><<<gmm, blk, 0, stream>>>(k_in, Wk_bf, bk, kbuf);
  gemm_projA<0><<<gmm, blk, 0, stream>>>(v_in, Wv_bf, bv, vbuf);

  // 3) kv = sum_s k^T v (+ ksum via ones-MFMA), split-K then finish
  gemm_kv<<<dim3(32, 16), blk, 0, stream>>>(kbuf, vbuf, kvpart, ksumpart);
  kv_finish<<<dim3(32), blk, 0, stream>>>(kvpart, ksumpart, kvT);

  // 4) y = (q @ kv) / (q . ksum + eps), bf16 in place over q buffer
  gemm_qkv<<<dim3(32, 64), blk, 0, stream>>>(qbuf, kvT);

  // 5) Output projection -> fp32 d_out
  gemm_bf16<0, 1><<<gmm, blk, 0, stream>>>(qbuf, Wp_bf, bp, out);
}